// Round 1
// baseline (1031.970 us; speedup 1.0000x reference)
//
#include <hip/hip_runtime.h>
#include <hip/hip_bf16.h>

// Problem constants
constexpr int NHRZ = 2048, BATCH = 128, NU = 64, NY = 64, NH = 256, H = 128;
constexpr int CHUNK = 64;              // time steps per chunk
constexpr int NCHUNK = NHRZ / CHUNK;   // 32 chunks

// ---------------------------------------------------------------------------
// Chunked scan kernel.
//  FINAL=false: local scan with zero init, writes chunk-end state -> ends
//  FINAL=true : scan with true init (starts), fused Y projection -> out
// One block per (chunk c, batch b). 256 threads, thread = state index h.
// ---------------------------------------------------------------------------
template <bool FINAL>
__global__ __launch_bounds__(256) void scan_kernel(
    const float* __restrict__ U,      // (NHRZ, BATCH, NU)
    const float* __restrict__ lre,    // (H,)
    const float* __restrict__ lim,    // (H,)
    const float* __restrict__ Bmat,   // (NH, NU)
    const float* __restrict__ Wx2y,   // (NY, NH)  [FINAL only]
    const float* __restrict__ bx2y,   // (NY,)     [FINAL only]
    const float* __restrict__ starts, // (NCHUNK, BATCH, NH) [FINAL only]
    float* __restrict__ ends,         // (NCHUNK, BATCH, NH) [!FINAL only]
    float* __restrict__ out)          // (NHRZ+1, BATCH, NY) [FINAL only]
{
    const int h   = threadIdx.x;          // 0..255
    const int blk = blockIdx.x;
    const int c   = blk >> 7;             // blk / BATCH
    const int b   = blk & (BATCH - 1);    // blk % BATCH
    const int hm  = h & (H - 1);
    const bool is_imag = h >= H;
    const int t0 = c * CHUNK;

    // lambda constants for this mode
    const float ar  = fabsf(lre[hm]);
    const float r   = expf(-ar);
    const float th  = 1.5707963267948966f * lim[hm];
    const float lr  = r * cosf(th);
    const float li  = r * sinf(th);
    const float nf  = sqrtf(fmaxf(0.0f, 1.0f - expf(-2.0f * ar)));

    // B row premultiplied by normalization factor (64 VGPRs)
    float Bs[NU];
#pragma unroll
    for (int u = 0; u < NU; ++u) Bs[u] = Bmat[h * NU + u] * nf;

    // Wx2y fragment for the fused Y projection (64 VGPRs, FINAL only).
    // thread -> (j = h>>2, part = h&3), holds Wx2y[j][part*64 .. part*64+63]
    float Wr[FINAL ? NU : 1];
    const int j    = h >> 2;
    const int part = h & 3;
    if constexpr (FINAL) {
#pragma unroll
        for (int i = 0; i < NU; ++i) Wr[i] = Wx2y[j * NH + part * 64 + i];
    }

    __shared__ float xs[2][NH];
    __shared__ float ub[2][NU];

    // Y projection from an LDS state vector (FINAL only)
    auto do_y = [&](const float* xv, int trow) {
        float acc = 0.0f;
#pragma unroll
        for (int k = 0; k < 16; ++k) {
            float4 xx = ((const float4*)(xv + part * 64))[k];
            acc = fmaf(Wr[4 * k + 0], xx.x, acc);
            acc = fmaf(Wr[4 * k + 1], xx.y, acc);
            acc = fmaf(Wr[4 * k + 2], xx.z, acc);
            acc = fmaf(Wr[4 * k + 3], xx.w, acc);
        }
        acc += __shfl_xor(acc, 1);
        acc += __shfl_xor(acc, 2);
        if (part == 0)
            out[((size_t)trow * BATCH + b) * NY + j] = acc + bx2y[j];
    };

    // init state
    float x_init;
    if constexpr (FINAL)
        x_init = starts[((size_t)c * BATCH + b) * NH + h];
    else
        x_init = 0.0f;
    xs[0][h] = x_init;
    // stage first U row
    if (h < 16)
        ((float4*)ub[0])[h] =
            ((const float4*)(U + ((size_t)t0 * BATCH + b) * NU))[h];
    __syncthreads();

    if constexpr (FINAL) {
        if (c == 0) do_y(xs[0], 0);   // Y row 0 = projection of x0
    }

    for (int t = 0; t < CHUNK; ++t) {
        const int cur = t & 1, nxt = cur ^ 1;
        // stage next U row (read next iter, after the sync)
        if (t + 1 < CHUNK && h < 16)
            ((float4*)ub[nxt])[h] =
                ((const float4*)(U + ((size_t)(t0 + t + 1) * BATCH + b) * NU))[h];
        // bu = dot(U_row, Bs)
        float a0 = 0.f, a1 = 0.f, a2 = 0.f, a3 = 0.f;
#pragma unroll
        for (int u = 0; u < NU; u += 4) {
            float4 uu = ((const float4*)ub[cur])[u >> 2];
            a0 = fmaf(uu.x, Bs[u + 0], a0);
            a1 = fmaf(uu.y, Bs[u + 1], a1);
            a2 = fmaf(uu.z, Bs[u + 2], a2);
            a3 = fmaf(uu.w, Bs[u + 3], a3);
        }
        const float bu = (a0 + a1) + (a2 + a3);
        // rotate + add
        const float x1 = xs[cur][hm];
        const float x2 = xs[cur][hm + H];
        const float xn = is_imag ? fmaf(li, x1, fmaf(lr, x2, bu))
                                 : fmaf(lr, x1, fmaf(-li, x2, bu));
        xs[nxt][h] = xn;
        __syncthreads();
        if constexpr (FINAL) do_y(xs[nxt], t0 + t + 1);
    }

    if constexpr (!FINAL)
        ends[((size_t)c * BATCH + b) * NH + h] = xs[CHUNK & 1][h];
}

// ---------------------------------------------------------------------------
// Sequential combine over chunks + x0 computation.
// One block per batch b, 128 threads = complex mode hm.
// ---------------------------------------------------------------------------
__global__ __launch_bounds__(128) void combine_kernel(
    const float* __restrict__ y0,    // (BATCH, NY)
    const float* __restrict__ Wy2x,  // (NH, NY)
    const float* __restrict__ by2x,  // (NH,)
    const float* __restrict__ lre,
    const float* __restrict__ lim,
    const float* __restrict__ ends,   // (NCHUNK, BATCH, NH)
    float* __restrict__ starts)       // (NCHUNK, BATCH, NH)
{
    const int b  = blockIdx.x;
    const int hm = threadIdx.x; // 0..127

    const float ab = fabsf(lre[hm]);
    const float r  = expf(-ab);
    const float th = 1.5707963267948966f * lim[hm];
    float lr = r * cosf(th);
    float li = r * sinf(th);
    // lambda^CHUNK by repeated squaring (CHUNK = 64 = 2^6)
    float pr = lr, pi = li;
#pragma unroll
    for (int k = 0; k < 6; ++k) {
        float nr = pr * pr - pi * pi;
        float ni = 2.0f * pr * pi;
        pr = nr; pi = ni;
    }

    // x0 = y0 @ Wy2x^T + by2x
    float s1 = by2x[hm];
    float s2 = by2x[hm + H];
#pragma unroll 8
    for (int q = 0; q < NY; ++q) {
        const float yv = y0[b * NY + q];
        s1 = fmaf(Wy2x[hm * NY + q], yv, s1);
        s2 = fmaf(Wy2x[(hm + H) * NY + q], yv, s2);
    }

    for (int c = 0; c < NCHUNK; ++c) {
        const size_t base = ((size_t)c * BATCH + b) * NH;
        starts[base + hm]     = s1;
        starts[base + hm + H] = s2;
        const float e1 = ends[base + hm];
        const float e2 = ends[base + hm + H];
        const float n1 = fmaf(pr, s1, fmaf(-pi, s2, e1));
        const float n2 = fmaf(pi, s1, fmaf(pr, s2, e2));
        s1 = n1; s2 = n2;
    }
}

extern "C" void kernel_launch(void* const* d_in, const int* in_sizes, int n_in,
                              void* d_out, int out_size, void* d_ws, size_t ws_size,
                              hipStream_t stream) {
    const float* y0   = (const float*)d_in[0];
    const float* U    = (const float*)d_in[1];
    const float* lre  = (const float*)d_in[2];
    const float* lim  = (const float*)d_in[3];
    const float* Bmat = (const float*)d_in[4];
    const float* Wy2x = (const float*)d_in[5];
    const float* by2x = (const float*)d_in[6];
    const float* Wx2y = (const float*)d_in[7];
    const float* bx2y = (const float*)d_in[8];
    float* out = (float*)d_out;

    float* ends   = (float*)d_ws;                       // NCHUNK*BATCH*NH f32 = 4 MB
    float* starts = ends + (size_t)NCHUNK * BATCH * NH; // another 4 MB

    const int grid = NCHUNK * BATCH; // 4096 blocks

    scan_kernel<false><<<grid, 256, 0, stream>>>(
        U, lre, lim, Bmat, nullptr, nullptr, nullptr, ends, nullptr);
    combine_kernel<<<BATCH, 128, 0, stream>>>(
        y0, Wy2x, by2x, lre, lim, ends, starts);
    scan_kernel<true><<<grid, 256, 0, stream>>>(
        U, lre, lim, Bmat, Wx2y, bx2y, starts, nullptr, out);
}

// Round 2
// 121.214 us; speedup vs baseline: 8.5136x; 8.5136x over previous
//
#include <hip/hip_runtime.h>
#include <hip/hip_bf16.h>

typedef __bf16 bf16x8 __attribute__((ext_vector_type(8)));
typedef float  f32x4  __attribute__((ext_vector_type(4)));

constexpr int kNHRZ = 2048, kBATCH = 128, kNU = 64, kNY = 64, kNH = 256, kH = 128;
constexpr int kCHUNK = 64, kNCHUNK = kNHRZ / kCHUNK;   // 32 chunks
constexpr int kTS = 16, kBT = 2, kM = kTS * kBT;       // 32 (t,b) rows per subtile
constexpr int kNSUB = kCHUNK / kTS;                    // 4 subtiles per chunk

// LDS strides (elements), padded for bank-conflict-free access
constexpr int U_STR = 72;    // bf16, 144 B rows (16B aligned)
constexpr int BU_STR = 260;  // f32
constexpr int X_STR = 264;   // bf16, 528 B rows (16B aligned)
constexpr int Y_STR = 68;    // f32, 272 B rows (16B aligned)

constexpr int OFF_U  = 0;
constexpr int OFF_BU = OFF_U + kM * U_STR * 2;     // 4608
constexpr int OFF_X  = OFF_BU + kM * BU_STR * 4;   // 37888
constexpr int OFF_Y  = OFF_X + kM * X_STR * 2;     // 54784
constexpr int SMEM1  = OFF_X;                      // pass1: U + Bu = 37888 B
constexpr int SMEM2  = OFF_Y + kM * Y_STR * 4;     // pass2: 63488 B (< 64 KB)

__device__ inline bf16x8 pack8(float4 a, float4 b) {
    bf16x8 v;
    v[0] = (__bf16)a.x; v[1] = (__bf16)a.y; v[2] = (__bf16)a.z; v[3] = (__bf16)a.w;
    v[4] = (__bf16)b.x; v[5] = (__bf16)b.y; v[6] = (__bf16)b.z; v[7] = (__bf16)b.w;
    return v;
}

// ---------------------------------------------------------------------------
// Fused per-chunk kernel: [stage U -> bf16 MFMA Bu-GEMM -> register scan ->
// (FINAL) bf16 MFMA Y-GEMM -> coalesced store].
// Block = (chunk c, batch pair). 256 threads = 4 waves.
// MFMA 16x16x32 bf16 layouts (gfx950):
//   A: row = lane&15, k = (lane>>4)*8 + j   (8 contiguous k per lane)
//   B: col = lane&15, k = (lane>>4)*8 + j
//   C/D: col = lane&15, row = (lane>>4)*4 + i   [m89-verified]
// ---------------------------------------------------------------------------
template <bool FINAL>
__global__ __launch_bounds__(256, 2) void scan_mfma(
    const float* __restrict__ U,      // (NHRZ, BATCH, NU)
    const float* __restrict__ lre,    // (H,)
    const float* __restrict__ lim,    // (H,)
    const float* __restrict__ Bmat,   // (NH, NU)
    const float* __restrict__ Wx2y,   // (NY, NH)   [FINAL]
    const float* __restrict__ bx2y,   // (NY,)      [FINAL]
    const float* __restrict__ starts, // (NCHUNK, BATCH, NH) [FINAL]
    float* __restrict__ ends,         // (NCHUNK, BATCH, NH) [!FINAL]
    float* __restrict__ out)          // (NHRZ+1, BATCH, NY) [FINAL]
{
    extern __shared__ char smem[];
    __bf16* Us = (__bf16*)(smem + OFF_U);   // [kM][U_STR]
    float*  Bu = (float*)(smem + OFF_BU);   // [kM][BU_STR]
    __bf16* Xs = (__bf16*)(smem + OFF_X);   // [kM][X_STR]   (FINAL)
    float*  Ys = (float*)(smem + OFF_Y);    // [kM][Y_STR]   (FINAL)

    const int tid  = threadIdx.x;
    const int lane = tid & 63;
    const int w    = tid >> 6;            // wave 0..3
    const int lw   = lane & 15;
    const int lg   = lane >> 4;
    const int blk  = blockIdx.x;
    const int c    = blk >> 6;            // chunk 0..31
    const int bp   = blk & 63;            // batch pair 0..63
    const int bglob = bp * 2;
    const int t0   = c * kCHUNK;

    // --- B fragments in registers: wave w owns h-cols [w*64, w*64+64), nf folded in
    bf16x8 Bf[2][4];  // [ks][nt]
#pragma unroll
    for (int nt = 0; nt < 4; ++nt) {
        const int h  = w * 64 + nt * 16 + lw;
        const float ab = fabsf(lre[h & (kH - 1)]);
        const float nf = sqrtf(fmaxf(0.0f, 1.0f - expf(-2.0f * ab)));
#pragma unroll
        for (int ks = 0; ks < 2; ++ks) {
            const float* p = Bmat + h * kNU + ks * 32 + lg * 8;
            float4 f0 = ((const float4*)p)[0];
            float4 f1 = ((const float4*)p)[1];
            f0.x *= nf; f0.y *= nf; f0.z *= nf; f0.w *= nf;
            f1.x *= nf; f1.y *= nf; f1.z *= nf; f1.w *= nf;
            Bf[ks][nt] = pack8(f0, f1);
        }
    }

    // --- W fragments + bias in registers (FINAL): wave: Mtile = w&1, y in [(w>>1)*32, +32)
    bf16x8 Wf[8][2];
    float  bias[2] = {0.f, 0.f};
    if constexpr (FINAL) {
#pragma unroll
        for (int nt = 0; nt < 2; ++nt) {
            const int y = (w >> 1) * 32 + nt * 16 + lw;
            bias[nt] = bx2y[y];
#pragma unroll
            for (int ks = 0; ks < 8; ++ks) {
                const float* p = Wx2y + y * kNH + ks * 32 + lg * 8;
                Wf[ks][nt] = pack8(((const float4*)p)[0], ((const float4*)p)[1]);
            }
        }
    }

    // --- per-thread scan constants / state: thread = (hm, bl)
    const int hm = tid & 127;
    const int bl = tid >> 7;
    float lr, li;
    {
        const float ab = fabsf(lre[hm]);
        const float r  = expf(-ab);
        const float th = 1.5707963267948966f * lim[hm];
        lr = r * cosf(th);
        li = r * sinf(th);
    }
    float x1, x2;
    if constexpr (FINAL) {
        const size_t sb = ((size_t)c * kBATCH + bglob + bl) * kNH;
        x1 = starts[sb + hm];
        x2 = starts[sb + hm + kH];
    } else {
        x1 = 0.0f; x2 = 0.0f;
    }

    for (int s = 0; s < kNSUB; ++s) {
        // ---- stage U subtile (f32 -> bf16 -> LDS)
        {
            const int m = tid >> 3, q = tid & 7;
            const int t = t0 + s * kTS + (m >> 1);
            const int b = bglob + (m & 1);
            const float* p = U + ((size_t)t * kBATCH + b) * kNU + q * 8;
            *(bf16x8*)&Us[m * U_STR + q * 8] =
                pack8(((const float4*)p)[0], ((const float4*)p)[1]);
        }
        __syncthreads();  // U staged; prev scan's Bu reads done

        // ---- GEMM1: Bu[m][h] (M=32, N=256 split over waves, K=64)
        {
            f32x4 acc[2][4] = {};
#pragma unroll
            for (int ks = 0; ks < 2; ++ks) {
                bf16x8 a0 = *(const bf16x8*)&Us[(lw)      * U_STR + ks * 32 + lg * 8];
                bf16x8 a1 = *(const bf16x8*)&Us[(16 + lw) * U_STR + ks * 32 + lg * 8];
#pragma unroll
                for (int nt = 0; nt < 4; ++nt) {
                    acc[0][nt] = __builtin_amdgcn_mfma_f32_16x16x32_bf16(a0, Bf[ks][nt], acc[0][nt], 0, 0, 0);
                    acc[1][nt] = __builtin_amdgcn_mfma_f32_16x16x32_bf16(a1, Bf[ks][nt], acc[1][nt], 0, 0, 0);
                }
            }
#pragma unroll
            for (int mt = 0; mt < 2; ++mt)
#pragma unroll
                for (int nt = 0; nt < 4; ++nt)
#pragma unroll
                    for (int i = 0; i < 4; ++i)
                        Bu[(mt * 16 + lg * 4 + i) * BU_STR + w * 64 + nt * 16 + lw] = acc[mt][nt][i];
        }
        __syncthreads();  // Bu ready

        // ---- register scan, 16 steps (no barriers inside)
#pragma unroll
        for (int t = 0; t < kTS; ++t) {
            const int m = t * kBT + bl;
            const float bu1 = Bu[m * BU_STR + hm];
            const float bu2 = Bu[m * BU_STR + kH + hm];
            const float n1 = fmaf(lr, x1, fmaf(-li, x2, bu1));
            const float n2 = fmaf(li, x1, fmaf(lr, x2, bu2));
            x1 = n1; x2 = n2;
            if constexpr (FINAL) {
                Xs[m * X_STR + hm]      = (__bf16)x1;
                Xs[m * X_STR + kH + hm] = (__bf16)x2;
            }
        }

        if constexpr (FINAL) {
            __syncthreads();  // X ready
            // ---- Y GEMM: M=32 (mt=w&1), N=64 (y base (w>>1)*32), K=256
            {
                f32x4 acc[2] = {};
                const int mt = w & 1;
#pragma unroll
                for (int ks = 0; ks < 8; ++ks) {
                    bf16x8 a = *(const bf16x8*)&Xs[(mt * 16 + lw) * X_STR + ks * 32 + lg * 8];
                    acc[0] = __builtin_amdgcn_mfma_f32_16x16x32_bf16(a, Wf[ks][0], acc[0], 0, 0, 0);
                    acc[1] = __builtin_amdgcn_mfma_f32_16x16x32_bf16(a, Wf[ks][1], acc[1], 0, 0, 0);
                }
#pragma unroll
                for (int nt = 0; nt < 2; ++nt)
#pragma unroll
                    for (int i = 0; i < 4; ++i)
                        Ys[(mt * 16 + lg * 4 + i) * Y_STR + (w >> 1) * 32 + nt * 16 + lw] =
                            acc[nt][i] + bias[nt];
            }
            __syncthreads();  // Ysub ready
            // ---- coalesced store of Y subtile
            {
                const int m = tid >> 3, q = tid & 7;
                const int t = t0 + s * kTS + (m >> 1);
                const int b = bglob + (m & 1);
                float4 v0 = *(const float4*)&Ys[m * Y_STR + q * 8];
                float4 v1 = *(const float4*)&Ys[m * Y_STR + q * 8 + 4];
                float* o = out + ((size_t)(1 + t) * kBATCH + b) * kNY + q * 8;
                ((float4*)o)[0] = v0;
                ((float4*)o)[1] = v1;
            }
        }
    }

    if constexpr (!FINAL) {
        const size_t eb = ((size_t)c * kBATCH + bglob + bl) * kNH;
        ends[eb + hm]      = x1;
        ends[eb + hm + kH] = x2;
    }
}

// ---------------------------------------------------------------------------
// Sequential combine over chunks + x0 computation (unchanged from R1).
// ---------------------------------------------------------------------------
__global__ __launch_bounds__(128) void combine_kernel(
    const float* __restrict__ y0, const float* __restrict__ Wy2x,
    const float* __restrict__ by2x, const float* __restrict__ lre,
    const float* __restrict__ lim, const float* __restrict__ ends,
    float* __restrict__ starts)
{
    const int b  = blockIdx.x;
    const int hm = threadIdx.x;

    const float ab = fabsf(lre[hm]);
    const float r  = expf(-ab);
    const float th = 1.5707963267948966f * lim[hm];
    float lr = r * cosf(th);
    float li = r * sinf(th);
    float pr = lr, pi = li;
#pragma unroll
    for (int k = 0; k < 6; ++k) {  // lambda^64
        const float nr = pr * pr - pi * pi;
        const float ni = 2.0f * pr * pi;
        pr = nr; pi = ni;
    }

    float s1 = by2x[hm];
    float s2 = by2x[hm + kH];
#pragma unroll 8
    for (int q = 0; q < kNY; ++q) {
        const float yv = y0[b * kNY + q];
        s1 = fmaf(Wy2x[hm * kNY + q], yv, s1);
        s2 = fmaf(Wy2x[(hm + kH) * kNY + q], yv, s2);
    }

    for (int c = 0; c < kNCHUNK; ++c) {
        const size_t base = ((size_t)c * kBATCH + b) * kNH;
        starts[base + hm]      = s1;
        starts[base + hm + kH] = s2;
        const float e1 = ends[base + hm];
        const float e2 = ends[base + hm + kH];
        const float n1 = fmaf(pr, s1, fmaf(-pi, s2, e1));
        const float n2 = fmaf(pi, s1, fmaf(pr, s2, e2));
        s1 = n1; s2 = n2;
    }
}

// Y row 0 = Wx2y @ x0 + bx2y  (x0 = starts[c=0])
__global__ __launch_bounds__(64) void y0_kernel(
    const float* __restrict__ starts, const float* __restrict__ Wx2y,
    const float* __restrict__ bx2y, float* __restrict__ out)
{
    const int b = blockIdx.x;
    const int y = threadIdx.x;
    const float* x0 = starts + (size_t)b * kNH;
    float acc = bx2y[y];
#pragma unroll 4
    for (int h = 0; h < kNH; h += 4) {
        float4 xv = *(const float4*)&x0[h];
        float4 wv = *(const float4*)&Wx2y[y * kNH + h];
        acc = fmaf(wv.x, xv.x, acc);
        acc = fmaf(wv.y, xv.y, acc);
        acc = fmaf(wv.z, xv.z, acc);
        acc = fmaf(wv.w, xv.w, acc);
    }
    out[(size_t)b * kNY + y] = acc;
}

extern "C" void kernel_launch(void* const* d_in, const int* in_sizes, int n_in,
                              void* d_out, int out_size, void* d_ws, size_t ws_size,
                              hipStream_t stream) {
    const float* y0   = (const float*)d_in[0];
    const float* U    = (const float*)d_in[1];
    const float* lre  = (const float*)d_in[2];
    const float* lim  = (const float*)d_in[3];
    const float* Bmat = (const float*)d_in[4];
    const float* Wy2x = (const float*)d_in[5];
    const float* by2x = (const float*)d_in[6];
    const float* Wx2y = (const float*)d_in[7];
    const float* bx2y = (const float*)d_in[8];
    float* out = (float*)d_out;

    float* ends   = (float*)d_ws;                          // 4 MB
    float* starts = ends + (size_t)kNCHUNK * kBATCH * kNH; // 4 MB

    const int grid = kNCHUNK * (kBATCH / kBT);  // 2048 blocks

    scan_mfma<false><<<grid, 256, SMEM1, stream>>>(
        U, lre, lim, Bmat, nullptr, nullptr, nullptr, ends, nullptr);
    combine_kernel<<<kBATCH, 128, 0, stream>>>(
        y0, Wy2x, by2x, lre, lim, ends, starts);
    y0_kernel<<<kBATCH, 64, 0, stream>>>(starts, Wx2y, bx2y, out);
    scan_mfma<true><<<grid, 256, SMEM2, stream>>>(
        U, lre, lim, Bmat, Wx2y, bx2y, starts, nullptr, out);
}